// Round 2
// 1281.223 us; speedup vs baseline: 1.2522x; 1.2522x over previous
//
#include <hip/hip_runtime.h>
#include <math.h>

typedef float f32x4 __attribute__((ext_vector_type(4)));
typedef short bf16x8 __attribute__((ext_vector_type(8)));

#define G1S 264                 // G1/T LDS row stride in u16 (528 B = 33*16, 2-way bank alias)
#define BSS 40                  // staged-B row stride in u16 (80 B: 64 data + 16 pad, 2-way alias)
#define SLICE_U16 (256 * BSS)   // one kc-slice: 10240 u16 = 20480 B

__device__ __forceinline__ unsigned short f2bf(float f){
    unsigned int u = __builtin_bit_cast(unsigned int, f);
    u += 0x7FFFu + ((u >> 16) & 1u);
    return (unsigned short)(u >> 16);
}
__device__ __forceinline__ float bf2f(unsigned short s){
    unsigned int u = ((unsigned int)s) << 16;
    return __builtin_bit_cast(float, u);
}
// gelu with branchless erf (Abramowitz-Stegun 7.1.26, |eps| < 1.5e-7)
__device__ __forceinline__ float gelu_f(float x){
    float ax = fabsf(x) * 0.70710678118654752f;
    float t  = 1.0f / fmaf(0.3275911f, ax, 1.0f);
    float p  = t * (0.254829592f + t * (-0.284496736f + t * (1.421413741f
             + t * (-1.453152027f + t * 1.061405429f))));
    float e  = __expf(-ax * ax);
    float er = copysignf(1.0f - p * e, x);
    return 0.5f * x * (1.0f + er);
}
__device__ __forceinline__ bf16x8 pack8(const float* x){
    bf16x8 a;
    #pragma unroll
    for (int j = 0; j < 8; ++j) a[j] = (short)f2bf(x[j]);
    return a;
}

// async copy of one 20480-B kc-slice (20 chunks of 1024 B) into LDS, 8 waves.
// waves 0..7 take chunks {w, w+8}; waves 0..3 additionally take chunk w+16.
// LDS dest per instruction = wave-uniform base; HW adds lane*16.
__device__ __forceinline__ void stage20k(const unsigned short* __restrict__ g,
                                         unsigned short* l, int wave, int lane){
    const char* gp = (const char*)g + lane * 16;
    char* lp = (char*)l;
    const int c0 = wave * 1024;
    __builtin_amdgcn_global_load_lds(
        (const __attribute__((address_space(1))) void*)(gp + c0),
        (__attribute__((address_space(3))) void*)(lp + c0), 16, 0, 0);
    const int c1 = c0 + 8192;
    __builtin_amdgcn_global_load_lds(
        (const __attribute__((address_space(1))) void*)(gp + c1),
        (__attribute__((address_space(3))) void*)(lp + c1), 16, 0, 0);
    if (wave < 4){
        const int c2 = c0 + 16384;
        __builtin_amdgcn_global_load_lds(
            (const __attribute__((address_space(1))) void*)(gp + c2),
            (__attribute__((address_space(3))) void*)(lp + c2), 16, 0, 0);
    }
}

// Build sliced-padded bf16 B layout: dst[kc][n][BSS u16], data j<32 = src[kc*32+j][n] (0 if k>=K)
__global__ void prep_sliced(const float* __restrict__ src, unsigned short* __restrict__ dst,
                            int K, int KC){
    int idx = blockIdx.x * blockDim.x + threadIdx.x;
    if (idx >= KC * 256) return;
    int kc = idx >> 8, n = idx & 255;
    unsigned short* d = dst + (size_t)(kc * 256 + n) * BSS;
    #pragma unroll 4
    for (int j = 0; j < 32; ++j){
        int k = kc * 32 + j;
        float v = (k < K) ? src[(size_t)k * 256 + n] : 0.0f;
        d[j] = f2bf(v);
    }
}

// dst[n*KP + kp] = bf16(src[kp*NS + n]) with zero-fill (for small wc2)
__global__ void transpose_cast_kernel(const float* __restrict__ src,
                                      unsigned short* __restrict__ dst,
                                      int K, int KP, int NS, int ND){
    int idx = blockIdx.x * blockDim.x + threadIdx.x;
    if (idx >= ND * KP) return;
    int n = idx / KP, kp = idx % KP;
    float v = (kp < K && n < NS) ? src[(size_t)kp * NS + n] : 0.0f;
    dst[idx] = f2bf(v);
}

// Fused MLP + segment reduction. 128 rows/block, 8 waves (4 row-quarters x 2 col-halves),
// Mt=2 x Nt=8 per wave. 512 threads -> 2 waves/SIMD (was 1) for latency hiding.
__global__ __launch_bounds__(512, 2) void mlp_seg_kernel(
    const float* __restrict__ h, const float* __restrict__ sf,
    const float* __restrict__ b1a, const float* __restrict__ b2a,
    const unsigned short* __restrict__ w1s,   // 9 slices
    const unsigned short* __restrict__ w2s,   // 8 slices
    const int* __restrict__ seg,
    float* __restrict__ sums, float* __restrict__ cnts, int N)
{
    __shared__ unsigned short Bs[2][SLICE_U16];
    __shared__ unsigned short G1[128 * G1S];
    __shared__ int segs[128];

    const int tid  = threadIdx.x;
    const int wave = tid >> 6, lane = tid & 63;
    const int quad = lane >> 4, l16 = lane & 15;
    const int rh   = wave >> 1, ch = wave & 1;     // row-quarter (0..3), col-half
    const int blockRow = blockIdx.x * 128;

    if (tid < 128){
        int r = blockRow + tid;
        segs[tid] = (r < N) ? seg[r] : -1;
    }

    const int arow0 = blockRow + rh * 32 + l16;    // + mt*16

    f32x4 acc[2][8];
    #pragma unroll
    for (int mt = 0; mt < 2; ++mt)
        #pragma unroll
        for (int nt = 0; nt < 8; ++nt) acc[mt][nt] = (f32x4){0.f,0.f,0.f,0.f};

    float x[2][2][8];

    // A-load for GEMM1 kc (f32, h cols 0..255, sf cols 256..271, zero pad to 288)
    auto loadA = [&](int kc, float dst[2][8]){
        #pragma unroll
        for (int mt = 0; mt < 2; ++mt){
            const int r = arow0 + mt * 16;
            #pragma unroll
            for (int j = 0; j < 8; ++j) dst[mt][j] = 0.f;
            if (r < N){
                if (kc < 8){
                    const float4* p = reinterpret_cast<const float4*>(h + (size_t)r * 256 + kc * 32 + quad * 8);
                    float4 u = p[0], v = p[1];
                    dst[mt][0]=u.x; dst[mt][1]=u.y; dst[mt][2]=u.z; dst[mt][3]=u.w;
                    dst[mt][4]=v.x; dst[mt][5]=v.y; dst[mt][6]=v.z; dst[mt][7]=v.w;
                } else if (quad < 2){
                    const float4* p = reinterpret_cast<const float4*>(sf + (size_t)r * 16 + quad * 8);
                    float4 u = p[0], v = p[1];
                    dst[mt][0]=u.x; dst[mt][1]=u.y; dst[mt][2]=u.z; dst[mt][3]=u.w;
                    dst[mt][4]=v.x; dst[mt][5]=v.y; dst[mt][6]=v.z; dst[mt][7]=v.w;
                }
            }
        }
    };

    stage20k(w1s, Bs[0], wave, lane);
    loadA(0, x[0]);

    // ---------------- GEMM1: 9 kc slices ----------------
    #pragma unroll
    for (int kc = 0; kc < 9; ++kc){
        __syncthreads();  // drains staging vmcnt + aligns waves
        if (kc < 8) stage20k(w1s + (size_t)(kc + 1) * SLICE_U16, Bs[(kc + 1) & 1], wave, lane);
        else        stage20k(w2s, Bs[1], wave, lane);
        if (kc < 8) loadA(kc + 1, x[(kc + 1) & 1]);

        bf16x8 a[2];
        #pragma unroll
        for (int mt = 0; mt < 2; ++mt) a[mt] = pack8(x[kc & 1][mt]);
        #pragma unroll
        for (int nt = 0; nt < 8; ++nt){
            const bf16x8 b = *reinterpret_cast<const bf16x8*>(
                &Bs[kc & 1][(ch * 128 + nt * 16 + l16) * BSS + quad * 8]);
            #pragma unroll
            for (int mt = 0; mt < 2; ++mt)
                acc[mt][nt] = __builtin_amdgcn_mfma_f32_16x16x32_bf16(a[mt], b, acc[mt][nt], 0, 0, 0);
        }
    }

    // epilogue 1: gelu + bias -> G1 (bf16). C/D layout: col=l16, row=quad*4+reg
    {
        float bias1[8];
        #pragma unroll
        for (int nt = 0; nt < 8; ++nt) bias1[nt] = b1a[ch * 128 + nt * 16 + l16];
        const int er0 = rh * 32 + quad * 4;
        #pragma unroll
        for (int mt = 0; mt < 2; ++mt)
            #pragma unroll
            for (int nt = 0; nt < 8; ++nt){
                const int col = ch * 128 + nt * 16 + l16;
                #pragma unroll
                for (int r = 0; r < 4; ++r)
                    G1[(er0 + mt * 16 + r) * G1S + col] = f2bf(gelu_f(acc[mt][nt][r] + bias1[nt]));
            }
    }

    // ---------------- GEMM2: 8 kc slices, A from G1 ----------------
    #pragma unroll
    for (int mt = 0; mt < 2; ++mt)
        #pragma unroll
        for (int nt = 0; nt < 8; ++nt) acc[mt][nt] = (f32x4){0.f,0.f,0.f,0.f};

    #pragma unroll
    for (int j = 0; j < 8; ++j){
        __syncthreads();
        if (j < 7) stage20k(w2s + (size_t)(j + 1) * SLICE_U16, Bs[j & 1], wave, lane);

        bf16x8 a2[2];
        #pragma unroll
        for (int mt = 0; mt < 2; ++mt)
            a2[mt] = *reinterpret_cast<const bf16x8*>(
                &G1[(rh * 32 + mt * 16 + l16) * G1S + j * 32 + quad * 8]);
        #pragma unroll
        for (int nt = 0; nt < 8; ++nt){
            const bf16x8 b = *reinterpret_cast<const bf16x8*>(
                &Bs[(j + 1) & 1][(ch * 128 + nt * 16 + l16) * BSS + quad * 8]);
            #pragma unroll
            for (int mt = 0; mt < 2; ++mt)
                acc[mt][nt] = __builtin_amdgcn_mfma_f32_16x16x32_bf16(a2[mt], b, acc[mt][nt], 0, 0, 0);
        }
    }
    __syncthreads();   // all waves done reading G1

    // epilogue 2: + b2a -> G1 (bf16)
    {
        float bias2[8];
        #pragma unroll
        for (int nt = 0; nt < 8; ++nt) bias2[nt] = b2a[ch * 128 + nt * 16 + l16];
        const int er0 = rh * 32 + quad * 4;
        #pragma unroll
        for (int mt = 0; mt < 2; ++mt)
            #pragma unroll
            for (int nt = 0; nt < 8; ++nt){
                const int col = ch * 128 + nt * 16 + l16;
                #pragma unroll
                for (int r = 0; r < 4; ++r)
                    G1[(er0 + mt * 16 + r) * G1S + col] = f2bf(acc[mt][nt][r] + bias2[nt]);
            }
    }
    __syncthreads();

    // sorted-run segment reduction: 2 threads per column, 64 rows each.
    // A segment spanning the row-64 boundary gets two atomicAdds (still correct).
    const int c  = tid & 255;
    const int r0 = (tid >> 8) * 64;
    float run = 0.f, rl = 0.f;
    int cur = segs[r0];
    for (int rr = 0; rr < 64; ++rr){
        const int r = r0 + rr;
        int s = segs[r];
        if (s != cur){
            if (cur >= 0){
                atomicAdd(&sums[(size_t)cur * 256 + c], run);
                if (c == 0) atomicAdd(&cnts[cur], rl);
            }
            cur = s; run = 0.f; rl = 0.f;
        }
        if (s >= 0){
            run += bf2f(G1[r * G1S + c]);
            rl  += 1.f;
        }
    }
    if (cur >= 0){
        atomicAdd(&sums[(size_t)cur * 256 + c], run);
        if (c == 0) atomicAdd(&cnts[cur], rl);
    }
}

// head: out = gelu((sums/max(cnt,1)) @ Wc1 + bc1) @ Wc2 + bc2
__global__ __launch_bounds__(512, 2) void head_kernel(
    const float* __restrict__ sums, const float* __restrict__ cnts,
    const float* __restrict__ bc1, const float* __restrict__ bc2,
    const unsigned short* __restrict__ wc1s,  // 8 slices
    const unsigned short* __restrict__ wc2,   // [16 n][256 k] bf16
    float* __restrict__ out, int G)
{
    __shared__ unsigned short Bs[2][SLICE_U16];
    __shared__ unsigned short T[128 * G1S];

    const int tid  = threadIdx.x;
    const int wave = tid >> 6, lane = tid & 63;
    const int quad = lane >> 4, l16 = lane & 15;
    const int rh   = wave >> 1, ch = wave & 1;
    const int blockRow = blockIdx.x * 128;
    const int grow0 = blockRow + rh * 32 + l16;

    float inv[2];
    #pragma unroll
    for (int mt = 0; mt < 2; ++mt){
        int r = grow0 + mt * 16;
        float c = (r < G) ? cnts[r] : 1.f;
        inv[mt] = 1.f / fmaxf(c, 1.f);
    }

    f32x4 acc[2][8];
    #pragma unroll
    for (int mt = 0; mt < 2; ++mt)
        #pragma unroll
        for (int nt = 0; nt < 8; ++nt) acc[mt][nt] = (f32x4){0.f,0.f,0.f,0.f};

    float x[2][2][8];
    auto loadA = [&](int kc, float dst[2][8]){
        #pragma unroll
        for (int mt = 0; mt < 2; ++mt){
            const int r = grow0 + mt * 16;
            #pragma unroll
            for (int j = 0; j < 8; ++j) dst[mt][j] = 0.f;
            if (r < G){
                const float4* p = reinterpret_cast<const float4*>(sums + (size_t)r * 256 + kc * 32 + quad * 8);
                float4 u = p[0], v = p[1];
                float s = inv[mt];
                dst[mt][0]=u.x*s; dst[mt][1]=u.y*s; dst[mt][2]=u.z*s; dst[mt][3]=u.w*s;
                dst[mt][4]=v.x*s; dst[mt][5]=v.y*s; dst[mt][6]=v.z*s; dst[mt][7]=v.w*s;
            }
        }
    };

    stage20k(wc1s, Bs[0], wave, lane);
    loadA(0, x[0]);

    #pragma unroll
    for (int kc = 0; kc < 8; ++kc){
        __syncthreads();
        if (kc < 7){
            stage20k(wc1s + (size_t)(kc + 1) * SLICE_U16, Bs[(kc + 1) & 1], wave, lane);
            loadA(kc + 1, x[(kc + 1) & 1]);
        }
        bf16x8 a[2];
        #pragma unroll
        for (int mt = 0; mt < 2; ++mt) a[mt] = pack8(x[kc & 1][mt]);
        #pragma unroll
        for (int nt = 0; nt < 8; ++nt){
            const bf16x8 b = *reinterpret_cast<const bf16x8*>(
                &Bs[kc & 1][(ch * 128 + nt * 16 + l16) * BSS + quad * 8]);
            #pragma unroll
            for (int mt = 0; mt < 2; ++mt)
                acc[mt][nt] = __builtin_amdgcn_mfma_f32_16x16x32_bf16(a[mt], b, acc[mt][nt], 0, 0, 0);
        }
    }

    // epilogue: gelu + bc1 -> T
    {
        float bias1[8];
        #pragma unroll
        for (int nt = 0; nt < 8; ++nt) bias1[nt] = bc1[ch * 128 + nt * 16 + l16];
        const int er0 = rh * 32 + quad * 4;
        #pragma unroll
        for (int mt = 0; mt < 2; ++mt)
            #pragma unroll
            for (int nt = 0; nt < 8; ++nt){
                const int col = ch * 128 + nt * 16 + l16;
                #pragma unroll
                for (int r = 0; r < 4; ++r)
                    T[(er0 + mt * 16 + r) * G1S + col] = f2bf(gelu_f(acc[mt][nt][r] + bias1[nt]));
            }
    }
    __syncthreads();

    // GEMM2: [128x256] @ [256x16]; wave handles rows wave*16 .. +16
    f32x4 o = (f32x4){0.f,0.f,0.f,0.f};
    #pragma unroll
    for (int j = 0; j < 8; ++j){
        const bf16x8 a0 = *reinterpret_cast<const bf16x8*>(
            &T[(wave * 16 + l16) * G1S + j * 32 + quad * 8]);
        const bf16x8 b = *reinterpret_cast<const bf16x8*>(wc2 + (size_t)l16 * 256 + j * 32 + quad * 8);
        o = __builtin_amdgcn_mfma_f32_16x16x32_bf16(a0, b, o, 0, 0, 0);
    }

    if (l16 < 10){
        const float bias = bc2[l16];
        #pragma unroll
        for (int r = 0; r < 4; ++r){
            int g = blockRow + wave * 16 + quad * 4 + r;
            if (g < G) out[(size_t)g * 10 + l16] = o[r] + bias;
        }
    }
}

extern "C" void kernel_launch(void* const* d_in, const int* in_sizes, int n_in,
                              void* d_out, int out_size, void* d_ws, size_t ws_size,
                              hipStream_t stream)
{
    (void)n_in; (void)ws_size;
    const float* h   = (const float*)d_in[0];
    const float* sf  = (const float*)d_in[1];
    const float* W1a = (const float*)d_in[2];
    const float* b1a = (const float*)d_in[3];
    const float* W2a = (const float*)d_in[4];
    const float* b2a = (const float*)d_in[5];
    const float* Wc1 = (const float*)d_in[6];
    const float* bc1 = (const float*)d_in[7];
    const float* Wc2 = (const float*)d_in[8];
    const float* bc2 = (const float*)d_in[9];
    const int*   seg = (const int*)d_in[10];

    const int N = in_sizes[10];          // 500000
    const int C = in_sizes[9];           // 10
    const int G = out_size / C;          // 100000

    char* ws = (char*)d_ws;
    size_t off = 0;
    float* sums = (float*)(ws + off); off += (size_t)G * 256 * 4;
    float* cnts = (float*)(ws + off); off += (size_t)G * 4;
    off = (off + 255) & ~(size_t)255;
    unsigned short* w1s  = (unsigned short*)(ws + off); off += (size_t)9 * SLICE_U16 * 2;
    unsigned short* w2s  = (unsigned short*)(ws + off); off += (size_t)8 * SLICE_U16 * 2;
    unsigned short* wc1s = (unsigned short*)(ws + off); off += (size_t)8 * SLICE_U16 * 2;
    unsigned short* wc2t = (unsigned short*)(ws + off); off += (size_t)16 * 256 * 2;

    hipMemsetAsync(sums, 0, (size_t)G * 256 * 4 + (size_t)G * 4, stream);

    dim3 b256(256), b512(512);
    prep_sliced<<<(9 * 256 + 255) / 256, b256, 0, stream>>>(W1a, w1s, 272, 9);
    prep_sliced<<<(8 * 256 + 255) / 256, b256, 0, stream>>>(W2a, w2s, 256, 8);
    prep_sliced<<<(8 * 256 + 255) / 256, b256, 0, stream>>>(Wc1, wc1s, 256, 8);
    transpose_cast_kernel<<<(16 * 256 + 255) / 256, b256, 0, stream>>>(Wc2, wc2t, 256, 256, 10, 16);

    mlp_seg_kernel<<<(N + 127) / 128, b512, 0, stream>>>(
        h, sf, b1a, b2a, w1s, w2s, seg, sums, cnts, N);
    head_kernel<<<(G + 127) / 128, b512, 0, stream>>>(
        sums, cnts, bc1, bc2, wc1s, wc2t, (float*)d_out, G);
}

// Round 3
// 1234.062 us; speedup vs baseline: 1.3000x; 1.0382x over previous
//
#include <hip/hip_runtime.h>
#include <math.h>

typedef float f32x4 __attribute__((ext_vector_type(4)));
typedef short bf16x8 __attribute__((ext_vector_type(8)));

#define G1S 264                 // G1/T LDS row stride in u16 (528 B = 33*16, 2-way bank alias)
#define BSS 40                  // staged-B row stride in u16 (80 B: 64 data + 16 pad, 2-way alias)
#define SLICE_U16 (256 * BSS)   // one kc-slice: 10240 u16 = 20480 B

__device__ __forceinline__ unsigned short f2bf(float f){
    unsigned int u = __builtin_bit_cast(unsigned int, f);
    u += 0x7FFFu + ((u >> 16) & 1u);
    return (unsigned short)(u >> 16);
}
__device__ __forceinline__ float bf2f(unsigned short s){
    unsigned int u = ((unsigned int)s) << 16;
    return __builtin_bit_cast(float, u);
}
// gelu with branchless erf (Abramowitz-Stegun 7.1.26, |eps| < 1.5e-7)
__device__ __forceinline__ float gelu_f(float x){
    float ax = fabsf(x) * 0.70710678118654752f;
    float t  = 1.0f / fmaf(0.3275911f, ax, 1.0f);
    float p  = t * (0.254829592f + t * (-0.284496736f + t * (1.421413741f
             + t * (-1.453152027f + t * 1.061405429f))));
    float e  = __expf(-ax * ax);
    float er = copysignf(1.0f - p * e, x);
    return 0.5f * x * (1.0f + er);
}
__device__ __forceinline__ bf16x8 pack8(const float* x){
    bf16x8 a;
    #pragma unroll
    for (int j = 0; j < 8; ++j) a[j] = (short)f2bf(x[j]);
    return a;
}

// async copy of one 20480-B kc-slice (20 chunks of 1024 B) into LDS, 8 waves.
// waves 0..7 take chunks {w, w+8}; waves 0..3 additionally take chunk w+16.
// LDS dest per instruction = wave-uniform base; HW adds lane*16.
__device__ __forceinline__ void stage20k(const unsigned short* __restrict__ g,
                                         unsigned short* l, int wave, int lane){
    const char* gp = (const char*)g + lane * 16;
    char* lp = (char*)l;
    const int c0 = wave * 1024;
    __builtin_amdgcn_global_load_lds(
        (const __attribute__((address_space(1))) void*)(gp + c0),
        (__attribute__((address_space(3))) void*)(lp + c0), 16, 0, 0);
    const int c1 = c0 + 8192;
    __builtin_amdgcn_global_load_lds(
        (const __attribute__((address_space(1))) void*)(gp + c1),
        (__attribute__((address_space(3))) void*)(lp + c1), 16, 0, 0);
    if (wave < 4){
        const int c2 = c0 + 16384;
        __builtin_amdgcn_global_load_lds(
            (const __attribute__((address_space(1))) void*)(gp + c2),
            (__attribute__((address_space(3))) void*)(lp + c2), 16, 0, 0);
    }
}

// Build sliced-padded bf16 B layout: dst[kc][n][BSS u16], data j<32 = src[kc*32+j][n] (0 if k>=K)
__global__ void prep_sliced(const float* __restrict__ src, unsigned short* __restrict__ dst,
                            int K, int KC){
    int idx = blockIdx.x * blockDim.x + threadIdx.x;
    if (idx >= KC * 256) return;
    int kc = idx >> 8, n = idx & 255;
    unsigned short* d = dst + (size_t)(kc * 256 + n) * BSS;
    #pragma unroll 4
    for (int j = 0; j < 32; ++j){
        int k = kc * 32 + j;
        float v = (k < K) ? src[(size_t)k * 256 + n] : 0.0f;
        d[j] = f2bf(v);
    }
}

// dst[n*KP + kp] = bf16(src[kp*NS + n]) with zero-fill (for small wc2)
__global__ void transpose_cast_kernel(const float* __restrict__ src,
                                      unsigned short* __restrict__ dst,
                                      int K, int KP, int NS, int ND){
    int idx = blockIdx.x * blockDim.x + threadIdx.x;
    if (idx >= ND * KP) return;
    int n = idx / KP, kp = idx % KP;
    float v = (kp < K && n < NS) ? src[(size_t)kp * NS + n] : 0.0f;
    dst[idx] = f2bf(v);
}

// Fused MLP + segment reduction. 64 rows/block, 8 waves (2 row-halves x 4 col-quarters),
// Mt=2 x Nt=4 per wave. LDS ~75 KB -> 2 blocks/CU = 4 waves/SIMD in two
// independent barrier domains (block A computes while block B drains).
__global__ __launch_bounds__(512, 4) void mlp_seg_kernel(
    const float* __restrict__ h, const float* __restrict__ sf,
    const float* __restrict__ b1a, const float* __restrict__ b2a,
    const unsigned short* __restrict__ w1s,   // 9 slices
    const unsigned short* __restrict__ w2s,   // 8 slices
    const int* __restrict__ seg,
    float* __restrict__ sums, float* __restrict__ cnts, int N)
{
    __shared__ unsigned short Bs[2][SLICE_U16];   // 40960 B
    __shared__ unsigned short G1[64 * G1S];       // 33792 B
    __shared__ int segs[64];

    const int tid  = threadIdx.x;
    const int wave = tid >> 6, lane = tid & 63;
    const int quad = lane >> 4, l16 = lane & 15;
    const int rh   = wave >> 2, cq = wave & 3;    // row-half (0..1), col-quarter (0..3)
    const int blockRow = blockIdx.x * 64;

    if (tid < 64){
        int r = blockRow + tid;
        segs[tid] = (r < N) ? seg[r] : -1;
    }

    const int arow0 = blockRow + rh * 32 + l16;   // + mt*16

    f32x4 acc[2][4];
    #pragma unroll
    for (int mt = 0; mt < 2; ++mt)
        #pragma unroll
        for (int nt = 0; nt < 4; ++nt) acc[mt][nt] = (f32x4){0.f,0.f,0.f,0.f};

    float x[2][2][8];

    // A-load for GEMM1 kc (f32, h cols 0..255, sf cols 256..271, zero pad to 288)
    auto loadA = [&](int kc, float dst[2][8]){
        #pragma unroll
        for (int mt = 0; mt < 2; ++mt){
            const int r = arow0 + mt * 16;
            #pragma unroll
            for (int j = 0; j < 8; ++j) dst[mt][j] = 0.f;
            if (r < N){
                if (kc < 8){
                    const float4* p = reinterpret_cast<const float4*>(h + (size_t)r * 256 + kc * 32 + quad * 8);
                    float4 u = p[0], v = p[1];
                    dst[mt][0]=u.x; dst[mt][1]=u.y; dst[mt][2]=u.z; dst[mt][3]=u.w;
                    dst[mt][4]=v.x; dst[mt][5]=v.y; dst[mt][6]=v.z; dst[mt][7]=v.w;
                } else if (quad < 2){
                    const float4* p = reinterpret_cast<const float4*>(sf + (size_t)r * 16 + quad * 8);
                    float4 u = p[0], v = p[1];
                    dst[mt][0]=u.x; dst[mt][1]=u.y; dst[mt][2]=u.z; dst[mt][3]=u.w;
                    dst[mt][4]=v.x; dst[mt][5]=v.y; dst[mt][6]=v.z; dst[mt][7]=v.w;
                }
            }
        }
    };

    stage20k(w1s, Bs[0], wave, lane);
    loadA(0, x[0]);

    // ---------------- GEMM1: 9 kc slices ----------------
    #pragma unroll
    for (int kc = 0; kc < 9; ++kc){
        __syncthreads();  // drains staging vmcnt + aligns waves
        if (kc < 8) stage20k(w1s + (size_t)(kc + 1) * SLICE_U16, Bs[(kc + 1) & 1], wave, lane);
        else        stage20k(w2s, Bs[1], wave, lane);
        if (kc < 8) loadA(kc + 1, x[(kc + 1) & 1]);

        bf16x8 a[2];
        #pragma unroll
        for (int mt = 0; mt < 2; ++mt) a[mt] = pack8(x[kc & 1][mt]);
        #pragma unroll
        for (int nt = 0; nt < 4; ++nt){
            const bf16x8 b = *reinterpret_cast<const bf16x8*>(
                &Bs[kc & 1][(cq * 64 + nt * 16 + l16) * BSS + quad * 8]);
            #pragma unroll
            for (int mt = 0; mt < 2; ++mt)
                acc[mt][nt] = __builtin_amdgcn_mfma_f32_16x16x32_bf16(a[mt], b, acc[mt][nt], 0, 0, 0);
        }
    }

    // epilogue 1: gelu + bias -> G1 (bf16). C/D layout: col=l16, row=quad*4+reg
    {
        float bias1[4];
        #pragma unroll
        for (int nt = 0; nt < 4; ++nt) bias1[nt] = b1a[cq * 64 + nt * 16 + l16];
        const int er0 = rh * 32 + quad * 4;
        #pragma unroll
        for (int mt = 0; mt < 2; ++mt)
            #pragma unroll
            for (int nt = 0; nt < 4; ++nt){
                const int col = cq * 64 + nt * 16 + l16;
                #pragma unroll
                for (int r = 0; r < 4; ++r)
                    G1[(er0 + mt * 16 + r) * G1S + col] = f2bf(gelu_f(acc[mt][nt][r] + bias1[nt]));
            }
    }

    // ---------------- GEMM2: 8 kc slices, A from G1 ----------------
    #pragma unroll
    for (int mt = 0; mt < 2; ++mt)
        #pragma unroll
        for (int nt = 0; nt < 4; ++nt) acc[mt][nt] = (f32x4){0.f,0.f,0.f,0.f};

    #pragma unroll
    for (int j = 0; j < 8; ++j){
        __syncthreads();
        if (j < 7) stage20k(w2s + (size_t)(j + 1) * SLICE_U16, Bs[j & 1], wave, lane);

        bf16x8 a2[2];
        #pragma unroll
        for (int mt = 0; mt < 2; ++mt)
            a2[mt] = *reinterpret_cast<const bf16x8*>(
                &G1[(rh * 32 + mt * 16 + l16) * G1S + j * 32 + quad * 8]);
        #pragma unroll
        for (int nt = 0; nt < 4; ++nt){
            const bf16x8 b = *reinterpret_cast<const bf16x8*>(
                &Bs[(j + 1) & 1][(cq * 64 + nt * 16 + l16) * BSS + quad * 8]);
            #pragma unroll
            for (int mt = 0; mt < 2; ++mt)
                acc[mt][nt] = __builtin_amdgcn_mfma_f32_16x16x32_bf16(a2[mt], b, acc[mt][nt], 0, 0, 0);
        }
    }
    __syncthreads();   // all waves done reading G1

    // epilogue 2: + b2a -> G1 (bf16)
    {
        float bias2[4];
        #pragma unroll
        for (int nt = 0; nt < 4; ++nt) bias2[nt] = b2a[cq * 64 + nt * 16 + l16];
        const int er0 = rh * 32 + quad * 4;
        #pragma unroll
        for (int mt = 0; mt < 2; ++mt)
            #pragma unroll
            for (int nt = 0; nt < 4; ++nt){
                const int col = cq * 64 + nt * 16 + l16;
                #pragma unroll
                for (int r = 0; r < 4; ++r)
                    G1[(er0 + mt * 16 + r) * G1S + col] = f2bf(acc[mt][nt][r] + bias2[nt]);
            }
    }
    __syncthreads();

    // sorted-run segment reduction: 2 threads per column, 32 rows each.
    // A segment spanning the row-32 boundary gets two atomicAdds (still correct).
    const int c  = tid & 255;
    const int r0 = (tid >> 8) * 32;
    float run = 0.f, rl = 0.f;
    int cur = segs[r0];
    for (int rr = 0; rr < 32; ++rr){
        const int r = r0 + rr;
        int s = segs[r];
        if (s != cur){
            if (cur >= 0){
                atomicAdd(&sums[(size_t)cur * 256 + c], run);
                if (c == 0) atomicAdd(&cnts[cur], rl);
            }
            cur = s; run = 0.f; rl = 0.f;
        }
        if (s >= 0){
            run += bf2f(G1[r * G1S + c]);
            rl  += 1.f;
        }
    }
    if (cur >= 0){
        atomicAdd(&sums[(size_t)cur * 256 + c], run);
        if (c == 0) atomicAdd(&cnts[cur], rl);
    }
}

// head: out = gelu((sums/max(cnt,1)) @ Wc1 + bc1) @ Wc2 + bc2
// 64 rows/block, same 2x4 wave grid, 2 blocks/CU.
__global__ __launch_bounds__(512, 4) void head_kernel(
    const float* __restrict__ sums, const float* __restrict__ cnts,
    const float* __restrict__ bc1, const float* __restrict__ bc2,
    const unsigned short* __restrict__ wc1s,  // 8 slices
    const unsigned short* __restrict__ wc2,   // [16 n][256 k] bf16
    float* __restrict__ out, int G)
{
    __shared__ unsigned short Bs[2][SLICE_U16];
    __shared__ unsigned short T[64 * G1S];

    const int tid  = threadIdx.x;
    const int wave = tid >> 6, lane = tid & 63;
    const int quad = lane >> 4, l16 = lane & 15;
    const int rh   = wave >> 2, cq = wave & 3;
    const int blockRow = blockIdx.x * 64;
    const int grow0 = blockRow + rh * 32 + l16;

    float inv[2];
    #pragma unroll
    for (int mt = 0; mt < 2; ++mt){
        int r = grow0 + mt * 16;
        float c = (r < G) ? cnts[r] : 1.f;
        inv[mt] = 1.f / fmaxf(c, 1.f);
    }

    f32x4 acc[2][4];
    #pragma unroll
    for (int mt = 0; mt < 2; ++mt)
        #pragma unroll
        for (int nt = 0; nt < 4; ++nt) acc[mt][nt] = (f32x4){0.f,0.f,0.f,0.f};

    float x[2][2][8];
    auto loadA = [&](int kc, float dst[2][8]){
        #pragma unroll
        for (int mt = 0; mt < 2; ++mt){
            const int r = grow0 + mt * 16;
            #pragma unroll
            for (int j = 0; j < 8; ++j) dst[mt][j] = 0.f;
            if (r < G){
                const float4* p = reinterpret_cast<const float4*>(sums + (size_t)r * 256 + kc * 32 + quad * 8);
                float4 u = p[0], v = p[1];
                float s = inv[mt];
                dst[mt][0]=u.x*s; dst[mt][1]=u.y*s; dst[mt][2]=u.z*s; dst[mt][3]=u.w*s;
                dst[mt][4]=v.x*s; dst[mt][5]=v.y*s; dst[mt][6]=v.z*s; dst[mt][7]=v.w*s;
            }
        }
    };

    stage20k(wc1s, Bs[0], wave, lane);
    loadA(0, x[0]);

    #pragma unroll
    for (int kc = 0; kc < 8; ++kc){
        __syncthreads();
        if (kc < 7){
            stage20k(wc1s + (size_t)(kc + 1) * SLICE_U16, Bs[(kc + 1) & 1], wave, lane);
            loadA(kc + 1, x[(kc + 1) & 1]);
        }
        bf16x8 a[2];
        #pragma unroll
        for (int mt = 0; mt < 2; ++mt) a[mt] = pack8(x[kc & 1][mt]);
        #pragma unroll
        for (int nt = 0; nt < 4; ++nt){
            const bf16x8 b = *reinterpret_cast<const bf16x8*>(
                &Bs[kc & 1][(cq * 64 + nt * 16 + l16) * BSS + quad * 8]);
            #pragma unroll
            for (int mt = 0; mt < 2; ++mt)
                acc[mt][nt] = __builtin_amdgcn_mfma_f32_16x16x32_bf16(a[mt], b, acc[mt][nt], 0, 0, 0);
        }
    }

    // epilogue: gelu + bc1 -> T
    {
        float bias1[4];
        #pragma unroll
        for (int nt = 0; nt < 4; ++nt) bias1[nt] = bc1[cq * 64 + nt * 16 + l16];
        const int er0 = rh * 32 + quad * 4;
        #pragma unroll
        for (int mt = 0; mt < 2; ++mt)
            #pragma unroll
            for (int nt = 0; nt < 4; ++nt){
                const int col = cq * 64 + nt * 16 + l16;
                #pragma unroll
                for (int r = 0; r < 4; ++r)
                    T[(er0 + mt * 16 + r) * G1S + col] = f2bf(gelu_f(acc[mt][nt][r] + bias1[nt]));
            }
    }
    __syncthreads();

    // GEMM2: [64x256] @ [256x16]; waves 0..3 each handle 16 rows
    if (wave < 4){
        f32x4 o = (f32x4){0.f,0.f,0.f,0.f};
        #pragma unroll
        for (int j = 0; j < 8; ++j){
            const bf16x8 a0 = *reinterpret_cast<const bf16x8*>(
                &T[(wave * 16 + l16) * G1S + j * 32 + quad * 8]);
            const bf16x8 b = *reinterpret_cast<const bf16x8*>(wc2 + (size_t)l16 * 256 + j * 32 + quad * 8);
            o = __builtin_amdgcn_mfma_f32_16x16x32_bf16(a0, b, o, 0, 0, 0);
        }
        if (l16 < 10){
            const float bias = bc2[l16];
            #pragma unroll
            for (int r = 0; r < 4; ++r){
                int g = blockRow + wave * 16 + quad * 4 + r;
                if (g < G) out[(size_t)g * 10 + l16] = o[r] + bias;
            }
        }
    }
}

extern "C" void kernel_launch(void* const* d_in, const int* in_sizes, int n_in,
                              void* d_out, int out_size, void* d_ws, size_t ws_size,
                              hipStream_t stream)
{
    (void)n_in; (void)ws_size;
    const float* h   = (const float*)d_in[0];
    const float* sf  = (const float*)d_in[1];
    const float* W1a = (const float*)d_in[2];
    const float* b1a = (const float*)d_in[3];
    const float* W2a = (const float*)d_in[4];
    const float* b2a = (const float*)d_in[5];
    const float* Wc1 = (const float*)d_in[6];
    const float* bc1 = (const float*)d_in[7];
    const float* Wc2 = (const float*)d_in[8];
    const float* bc2 = (const float*)d_in[9];
    const int*   seg = (const int*)d_in[10];

    const int N = in_sizes[10];          // 500000
    const int C = in_sizes[9];           // 10
    const int G = out_size / C;          // 100000

    char* ws = (char*)d_ws;
    size_t off = 0;
    float* sums = (float*)(ws + off); off += (size_t)G * 256 * 4;
    float* cnts = (float*)(ws + off); off += (size_t)G * 4;
    off = (off + 255) & ~(size_t)255;
    unsigned short* w1s  = (unsigned short*)(ws + off); off += (size_t)9 * SLICE_U16 * 2;
    unsigned short* w2s  = (unsigned short*)(ws + off); off += (size_t)8 * SLICE_U16 * 2;
    unsigned short* wc1s = (unsigned short*)(ws + off); off += (size_t)8 * SLICE_U16 * 2;
    unsigned short* wc2t = (unsigned short*)(ws + off); off += (size_t)16 * 256 * 2;

    hipMemsetAsync(sums, 0, (size_t)G * 256 * 4 + (size_t)G * 4, stream);

    dim3 b256(256), b512(512);
    prep_sliced<<<(9 * 256 + 255) / 256, b256, 0, stream>>>(W1a, w1s, 272, 9);
    prep_sliced<<<(8 * 256 + 255) / 256, b256, 0, stream>>>(W2a, w2s, 256, 8);
    prep_sliced<<<(8 * 256 + 255) / 256, b256, 0, stream>>>(Wc1, wc1s, 256, 8);
    transpose_cast_kernel<<<(16 * 256 + 255) / 256, b256, 0, stream>>>(Wc2, wc2t, 256, 256, 10, 16);

    mlp_seg_kernel<<<(N + 63) / 64, b512, 0, stream>>>(
        h, sf, b1a, b2a, w1s, w2s, seg, sums, cnts, N);
    head_kernel<<<(G + 63) / 64, b512, 0, stream>>>(
        sums, cnts, bc1, bc2, wc1s, wc2t, (float*)d_out, G);
}